// Round 10
// baseline (244.030 us; speedup 1.0000x reference)
//
#include <hip/hip_runtime.h>
#include <math.h>

// GraphAttentionLayer, N=8192, D=256, fp32. Exact reformulation:
//   h = x@W + b ; s1 = h@a1 ; s2 = h@a2 ; c_i = s1_i + a_b
//   out_i = [A_i*SufEH(r_i) + Alo_i*PreFH(r_i)] / [A_i*sufE(r_i) + Alo_i*preF(r_i)]
//   E_j=exp(s2_j), F_j=exp(.01*s2_j), A=exp(c), Alo=exp(.01c),
//   r_i = lower_bound(sorted s2, -c_i)   (exact leaky_relu split).
// R7: dispatch-count experiment. R3 (8 dispatches, kd3-heavy) == R6 (8 dispatches,
// kd3 removed) == ~143us -> fixed per-dispatch overhead suspected. Merge
// memset+kb+kc+kc2 into ONE single-block ksort (LDS hist+scan+scatter+rank);
// drop cnt atomics from ka. 8 -> 5 dispatches, all else identical to R6.

#define NN 8192
#define DD 256
#define NB 8192
#define CH 512
#define POS (NN / CH)    /* 16 */
#define RANGE 8.0f
#define SCALE (NB / (2.0f * RANGE))
#define NEG_SLOPE 0.01f

__device__ __forceinline__ int bucket_of(float v) {
    v = fminf(fmaxf(v, -RANGE), RANGE);
    int b = (int)floorf((v + RANGE) * SCALE);
    if (b < 0) b = 0;
    if (b > NB - 1) b = NB - 1;
    return b;
}

// ---------------------------------------------------------------- KA: h = x@W+b, s1, s2
__global__ __launch_bounds__(256) void ka_gemm(
    const float* __restrict__ x, const float* __restrict__ W,
    const float* __restrict__ bfc, const float* __restrict__ a1,
    const float* __restrict__ a2,
    float* __restrict__ h, float* __restrict__ s1, float* __restrict__ s2)
{
    const int t = threadIdx.x;
    const int ct = t & 63;
    const int rt = t >> 6;
    const int row0 = blockIdx.x * 16;
    __shared__ float xs[16][DD];

#pragma unroll
    for (int i = 0; i < 4; ++i) {
        const int f = i * 256 + t;
        const int r = f >> 6, c4 = f & 63;
        *reinterpret_cast<float4*>(&xs[r][c4 * 4]) =
            *reinterpret_cast<const float4*>(&x[(size_t)(row0 + r) * DD + c4 * 4]);
    }
    __syncthreads();

    float acc[4][4];
#pragma unroll
    for (int r = 0; r < 4; ++r)
#pragma unroll
        for (int c = 0; c < 4; ++c) acc[r][c] = 0.f;

#pragma unroll 2
    for (int k4 = 0; k4 < DD / 4; ++k4) {
        float4 wv[4];
#pragma unroll
        for (int kk = 0; kk < 4; ++kk)
            wv[kk] = *reinterpret_cast<const float4*>(&W[(size_t)(k4 * 4 + kk) * DD + ct * 4]);
        float4 xr[4];
#pragma unroll
        for (int r = 0; r < 4; ++r)
            xr[r] = *reinterpret_cast<const float4*>(&xs[rt * 4 + r][k4 * 4]);
#pragma unroll
        for (int kk = 0; kk < 4; ++kk) {
#pragma unroll
            for (int r = 0; r < 4; ++r) {
                const float xv = (kk == 0) ? xr[r].x : (kk == 1) ? xr[r].y : (kk == 2) ? xr[r].z : xr[r].w;
                acc[r][0] = fmaf(xv, wv[kk].x, acc[r][0]);
                acc[r][1] = fmaf(xv, wv[kk].y, acc[r][1]);
                acc[r][2] = fmaf(xv, wv[kk].z, acc[r][2]);
                acc[r][3] = fmaf(xv, wv[kk].w, acc[r][3]);
            }
        }
    }

    const float4 bv  = *reinterpret_cast<const float4*>(&bfc[ct * 4]);
    const float4 a1v = *reinterpret_cast<const float4*>(&a1[ct * 4]);
    const float4 a2v = *reinterpret_cast<const float4*>(&a2[ct * 4]);
    const int lane = t & 63;

#pragma unroll
    for (int r = 0; r < 4; ++r) {
        acc[r][0] += bv.x; acc[r][1] += bv.y; acc[r][2] += bv.z; acc[r][3] += bv.w;
        const int row = row0 + rt * 4 + r;
        float4 hv = make_float4(acc[r][0], acc[r][1], acc[r][2], acc[r][3]);
        *reinterpret_cast<float4*>(&h[(size_t)row * DD + ct * 4]) = hv;
        float v1 = acc[r][0] * a1v.x + acc[r][1] * a1v.y + acc[r][2] * a1v.z + acc[r][3] * a1v.w;
        float v2 = acc[r][0] * a2v.x + acc[r][1] * a2v.y + acc[r][2] * a2v.z + acc[r][3] * a2v.w;
#pragma unroll
        for (int off = 32; off; off >>= 1) {
            v1 += __shfl_xor(v1, off, 64);
            v2 += __shfl_xor(v2, off, 64);
        }
        if (lane == 0) {
            s1[row] = v1;
            s2[row] = v2;
        }
    }
}

// ---------------------------------------------------------------- KSORT: 1 block — hist+scan+scatter+rank
// Replaces memset+kb+kc+kc2 (4 dispatches -> 1). LDS: A (hist->boff->cursor, 32KB int),
// B (ushort boff snapshot, 16KB), temp (1KB). perm staged in global (L2-hot, 32KB).
__global__ __launch_bounds__(256) void ksort(
    const float* __restrict__ s2, int* __restrict__ perm,
    int* __restrict__ perm2, float* __restrict__ s2s)
{
    __shared__ int A[NB];
    __shared__ unsigned short B[NB + 1];
    __shared__ int temp[256];
    const int t = threadIdx.x;

    for (int k = t; k < NB; k += 256) A[k] = 0;
    __syncthreads();

    for (int j = t; j < NN; j += 256) atomicAdd(&A[bucket_of(s2[j])], 1);
    __syncthreads();

    {   // exclusive scan of A in place; snapshot into B
        const int base = t * 32;
        int loc[32];
        int s = 0;
#pragma unroll
        for (int k = 0; k < 32; ++k) { loc[k] = s; s += A[base + k]; }
        temp[t] = s;
        __syncthreads();
        for (int off = 1; off < 256; off <<= 1) {
            const int v = (t >= off) ? temp[t - off] : 0;
            __syncthreads();
            temp[t] += v;
            __syncthreads();
        }
        const int excl = (t > 0) ? temp[t - 1] : 0;
#pragma unroll
        for (int k = 0; k < 32; ++k) {
            const int val = excl + loc[k];
            A[base + k] = val;                       // cursor
            B[base + k] = (unsigned short)val;       // preserved bounds
        }
        if (t == 0) B[NB] = (unsigned short)NN;
    }
    __syncthreads();

    for (int j = t; j < NN; j += 256) {              // scatter (bucket order, arbitrary within)
        const int bk = bucket_of(s2[j]);
        const int p = atomicAdd(&A[bk], 1);
        perm[p] = j;
    }
    __syncthreads();

    for (int j = t; j < NN; j += 256) {              // exact within-bucket rank -> sorted
        const float v = s2[j];
        const int bk = bucket_of(v);
        const int p0 = B[bk], p1 = B[bk + 1];
        int rank = 0;
        for (int p = p0; p < p1; ++p) {
            const int k = perm[p];
            const float vk = s2[k];
            rank += (vk < v) || (vk == v && k < j);
        }
        const int pos = p0 + rank;
        perm2[pos] = j;
        s2s[pos] = v;
    }
}

// ---------------------------------------------------------------- KD1: per-chunk totals, wave-per-chunk
__global__ __launch_bounds__(256) void kd1_tot(
    const float* __restrict__ h, const int* __restrict__ perm2,
    const float* __restrict__ s2s,
    float* __restrict__ TE, float* __restrict__ TF,
    float* __restrict__ sTE, float* __restrict__ sTF)
{
    const int w = threadIdx.x >> 6, lane = threadIdx.x & 63;
    const int c = blockIdx.x * 4 + w;
    const int p0 = c * POS;
    float vE[POS], vF[POS];
    int jj[POS];
#pragma unroll
    for (int k = 0; k < POS; ++k) {
        const float v = s2s[p0 + k];
        vE[k] = expf(v);
        vF[k] = expf(NEG_SLOPE * v);
        jj[k] = perm2[p0 + k];
    }
    float4 te = make_float4(0.f, 0.f, 0.f, 0.f);
    float4 tf = make_float4(0.f, 0.f, 0.f, 0.f);
#pragma unroll
    for (int k = 0; k < POS; ++k) {
        const float4 hv = *reinterpret_cast<const float4*>(&h[(size_t)jj[k] * DD + lane * 4]);
        te.x = fmaf(vE[k], hv.x, te.x); te.y = fmaf(vE[k], hv.y, te.y);
        te.z = fmaf(vE[k], hv.z, te.z); te.w = fmaf(vE[k], hv.w, te.w);
        tf.x = fmaf(vF[k], hv.x, tf.x); tf.y = fmaf(vF[k], hv.y, tf.y);
        tf.z = fmaf(vF[k], hv.z, tf.z); tf.w = fmaf(vF[k], hv.w, tf.w);
    }
    *reinterpret_cast<float4*>(&TE[(size_t)c * DD + lane * 4]) = te;
    *reinterpret_cast<float4*>(&TF[(size_t)c * DD + lane * 4]) = tf;
    if (lane == 0) {
        float se = 0.f, sf = 0.f;
#pragma unroll
        for (int k = 0; k < POS; ++k) { se += vE[k]; sf += vF[k]; }
        sTE[c] = se; sTF[c] = sf;
    }
}

// ---------------------------------------------------------------- 512-element exclusive scan, 256 threads
__device__ __forceinline__ void scan512_excl(float* lds, float* tmp, int t)
{
    const float a0 = lds[2 * t], a1 = lds[2 * t + 1];
    tmp[t] = a0 + a1;
    __syncthreads();
    for (int off = 1; off < 256; off <<= 1) {
        const float v = (t >= off) ? tmp[t - off] : 0.f;
        __syncthreads();
        tmp[t] += v;
        __syncthreads();
    }
    const float base = (t > 0) ? tmp[t - 1] : 0.f;
    lds[2 * t] = base;
    lds[2 * t + 1] = base + a0;
    __syncthreads();
}

// ---------------------------------------------------------------- KD2: chunk scans -> exclusive bases (+row CH)
__global__ __launch_bounds__(256) void kd2_scan(
    float* __restrict__ TE, float* __restrict__ TF,
    float* __restrict__ sTE, float* __restrict__ sTF)
{
    const int t = threadIdx.x;
    const int b = blockIdx.x;
    __shared__ float lds[CH];
    __shared__ float tmp[256];
    const int q0 = 2 * t, q1 = 2 * t + 1;

    if (b < 256) {
        const int d = b;
        lds[q0] = TE[(size_t)(511 - q0) * DD + d];
        lds[q1] = TE[(size_t)(511 - q1) * DD + d];
        __syncthreads();
        scan512_excl(lds, tmp, t);
        TE[(size_t)(511 - q0) * DD + d] = lds[q0];
        TE[(size_t)(511 - q1) * DD + d] = lds[q1];
        if (t == 0) TE[(size_t)CH * DD + d] = 0.f;
    } else if (b < 512) {
        const int d = b - 256;
        lds[q0] = TF[(size_t)q0 * DD + d];
        lds[q1] = TF[(size_t)q1 * DD + d];
        __syncthreads();
        scan512_excl(lds, tmp, t);
        TF[(size_t)q0 * DD + d] = lds[q0];
        TF[(size_t)q1 * DD + d] = lds[q1];
        if (t == 0) TF[(size_t)CH * DD + d] = tmp[255];
    } else {
        lds[q0] = sTE[511 - q0]; lds[q1] = sTE[511 - q1];
        __syncthreads();
        scan512_excl(lds, tmp, t);
        sTE[511 - q0] = lds[q0]; sTE[511 - q1] = lds[q1];
        if (t == 0) sTE[CH] = 0.f;
        __syncthreads();
        lds[q0] = sTF[q0]; lds[q1] = sTF[q1];
        __syncthreads();
        scan512_excl(lds, tmp, t);
        sTF[q0] = lds[q0]; sTF[q1] = lds[q1];
        if (t == 0) sTF[CH] = tmp[255];
    }
}

// ---------------------------------------------------------------- KE: output rows, wave-per-row
__global__ __launch_bounds__(256) void ke_out(
    const float* __restrict__ h, const float* __restrict__ s1,
    const float* __restrict__ s2s, const int* __restrict__ perm2,
    const float* __restrict__ TE, const float* __restrict__ TF,
    const float* __restrict__ sTE, const float* __restrict__ sTF,
    const float* __restrict__ ab, float* __restrict__ out)
{
    const int w = threadIdx.x >> 6, lane = threadIdx.x & 63;
    const int i = blockIdx.x * 4 + w;
    const float c = s1[i] + ab[0];
    const float tau = -c;
    const float A = expf(c);
    const float Alo = expf(NEG_SLOPE * c);

    int lo = 0, hi = NN;                 // r = lower_bound(s2s, tau)
    while (lo < hi) {
        const int mid = (lo + hi) >> 1;
        const bool lt = (s2s[mid] < tau);
        lo = lt ? (mid + 1) : lo;
        hi = lt ? hi : mid;
    }
    const int c0 = lo >> 4;              // chunk (POS=16)
    const int m = lo & 15;               // within-chunk split

    float4 numE = *reinterpret_cast<const float4*>(&TE[(size_t)c0 * DD + lane * 4]);
    float4 numF = *reinterpret_cast<const float4*>(&TF[(size_t)c0 * DD + lane * 4]);
    float denE = sTE[c0];
    float denF = sTF[c0];

    if (c0 < CH) {
        const int p0 = c0 * POS;
#pragma unroll
        for (int k = 0; k < POS; ++k) {
            const float v = s2s[p0 + k];
            const int j = perm2[p0 + k];
            const float4 hv = *reinterpret_cast<const float4*>(&h[(size_t)j * DD + lane * 4]);
            if (k >= m) {
                const float e = expf(v);
                numE.x = fmaf(e, hv.x, numE.x); numE.y = fmaf(e, hv.y, numE.y);
                numE.z = fmaf(e, hv.z, numE.z); numE.w = fmaf(e, hv.w, numE.w);
                denE += e;
            } else {
                const float f = expf(NEG_SLOPE * v);
                numF.x = fmaf(f, hv.x, numF.x); numF.y = fmaf(f, hv.y, numF.y);
                numF.z = fmaf(f, hv.z, numF.z); numF.w = fmaf(f, hv.w, numF.w);
                denF += f;
            }
        }
    }

    const float inv = 1.f / fmaf(A, denE, Alo * denF);
    float4 o;
    o.x = fmaf(A, numE.x, Alo * numF.x) * inv;
    o.y = fmaf(A, numE.y, Alo * numF.y) * inv;
    o.z = fmaf(A, numE.z, Alo * numF.z) * inv;
    o.w = fmaf(A, numE.w, Alo * numF.w) * inv;
    *reinterpret_cast<float4*>(&out[(size_t)i * DD + lane * 4]) = o;
}

// ----------------------------------------------------------------
extern "C" void kernel_launch(void* const* d_in, const int* in_sizes, int n_in,
                              void* d_out, int out_size, void* d_ws, size_t ws_size,
                              hipStream_t stream)
{
    const float* x   = (const float*)d_in[0];
    const float* W   = (const float*)d_in[1];
    const float* bfc = (const float*)d_in[2];
    const float* a1  = (const float*)d_in[3];
    const float* a2  = (const float*)d_in[4];
    const float* ab  = (const float*)d_in[5];
    float* out = (float*)d_out;

    float* h    = (float*)d_ws;                    // [N][D]
    float* TE   = h + (size_t)NN * DD;             // [CH+1][D]
    float* TF   = TE + (size_t)(CH + 1) * DD;      // [CH+1][D]
    float* s1   = TF + (size_t)(CH + 1) * DD;      // [N]
    float* s2   = s1 + NN;                         // [N]
    float* s2s  = s2 + NN;                         // [N]
    float* sTE  = s2s + NN;                        // [CH+1]
    float* sTF  = sTE + (CH + 1);                  // [CH+1]
    int* perm   = (int*)(sTF + (CH + 1));          // [N]
    int* perm2  = perm + NN;                       // [N]

    ka_gemm <<<NN / 16, 256, 0, stream>>>(x, W, bfc, a1, a2, h, s1, s2);
    ksort   <<<1, 256, 0, stream>>>(s2, perm, perm2, s2s);
    kd1_tot <<<CH / 4, 256, 0, stream>>>(h, perm2, s2s, TE, TF, sTE, sTF);
    kd2_scan<<<513, 256, 0, stream>>>(TE, TF, sTE, sTF);
    ke_out  <<<NN / 4, 256, 0, stream>>>(h, s1, s2s, perm2, TE, TF, sTE, sTF, ab, out);
}

// Round 12
// 146.012 us; speedup vs baseline: 1.6713x; 1.6713x over previous
//
#include <hip/hip_runtime.h>
#include <math.h>

// GraphAttentionLayer, N=8192, D=256, fp32. Exact reformulation:
//   h = x@W + b ; s1 = h@a1 ; s2 = h@a2 ; c_i = s1_i + a_b
//   out_i = [A_i*SufEH + Alo_i*PreFH] / [A_i*sufE + Alo_i*preF], split at s2_j >= -c_i.
// R10 resubmit (acquisition timeout; never measured).
// R9 post-mortem: single-block ksort(hist+scan+scatter+RANK) was 126us — the
// rank pass is a serial dependent-load chain on 1 CU. Fix: DROP the exact sort.
// ke uses Bt=bucket_of(tau) (no binary search), chunk bases at enclosing chunk
// boundaries, and enumerates full chunks [p0>>4..p1>>4] branching per element
// on s2>=tau — exact (buckets <Bt / >Bt compare consistently). ksort2 =
// hist+scan+scatter only, 1024 thr (16 waves), LDS-only hist; scatter also
// writes s2p (bucket-ordered values) for coalesced reads. 5 dispatches.

#define NN 8192
#define DD 256
#define NB 8192
#define CH 512
#define POS (NN / CH)    /* 16 */
#define RANGE 8.0f
#define SCALE (NB / (2.0f * RANGE))
#define NEG_SLOPE 0.01f

__device__ __forceinline__ int bucket_of(float v) {
    v = fminf(fmaxf(v, -RANGE), RANGE);
    int b = (int)floorf((v + RANGE) * SCALE);
    if (b < 0) b = 0;
    if (b > NB - 1) b = NB - 1;
    return b;
}

// ---------------------------------------------------------------- KA: h = x@W+b, s1, s2
__global__ __launch_bounds__(256) void ka_gemm(
    const float* __restrict__ x, const float* __restrict__ W,
    const float* __restrict__ bfc, const float* __restrict__ a1,
    const float* __restrict__ a2,
    float* __restrict__ h, float* __restrict__ s1, float* __restrict__ s2)
{
    const int t = threadIdx.x;
    const int ct = t & 63;
    const int rt = t >> 6;
    const int row0 = blockIdx.x * 16;
    __shared__ float xs[16][DD];

#pragma unroll
    for (int i = 0; i < 4; ++i) {
        const int f = i * 256 + t;
        const int r = f >> 6, c4 = f & 63;
        *reinterpret_cast<float4*>(&xs[r][c4 * 4]) =
            *reinterpret_cast<const float4*>(&x[(size_t)(row0 + r) * DD + c4 * 4]);
    }
    __syncthreads();

    float acc[4][4];
#pragma unroll
    for (int r = 0; r < 4; ++r)
#pragma unroll
        for (int c = 0; c < 4; ++c) acc[r][c] = 0.f;

#pragma unroll 2
    for (int k4 = 0; k4 < DD / 4; ++k4) {
        float4 wv[4];
#pragma unroll
        for (int kk = 0; kk < 4; ++kk)
            wv[kk] = *reinterpret_cast<const float4*>(&W[(size_t)(k4 * 4 + kk) * DD + ct * 4]);
        float4 xr[4];
#pragma unroll
        for (int r = 0; r < 4; ++r)
            xr[r] = *reinterpret_cast<const float4*>(&xs[rt * 4 + r][k4 * 4]);
#pragma unroll
        for (int kk = 0; kk < 4; ++kk) {
#pragma unroll
            for (int r = 0; r < 4; ++r) {
                const float xv = (kk == 0) ? xr[r].x : (kk == 1) ? xr[r].y : (kk == 2) ? xr[r].z : xr[r].w;
                acc[r][0] = fmaf(xv, wv[kk].x, acc[r][0]);
                acc[r][1] = fmaf(xv, wv[kk].y, acc[r][1]);
                acc[r][2] = fmaf(xv, wv[kk].z, acc[r][2]);
                acc[r][3] = fmaf(xv, wv[kk].w, acc[r][3]);
            }
        }
    }

    const float4 bv  = *reinterpret_cast<const float4*>(&bfc[ct * 4]);
    const float4 a1v = *reinterpret_cast<const float4*>(&a1[ct * 4]);
    const float4 a2v = *reinterpret_cast<const float4*>(&a2[ct * 4]);
    const int lane = t & 63;

#pragma unroll
    for (int r = 0; r < 4; ++r) {
        acc[r][0] += bv.x; acc[r][1] += bv.y; acc[r][2] += bv.z; acc[r][3] += bv.w;
        const int row = row0 + rt * 4 + r;
        float4 hv = make_float4(acc[r][0], acc[r][1], acc[r][2], acc[r][3]);
        *reinterpret_cast<float4*>(&h[(size_t)row * DD + ct * 4]) = hv;
        float v1 = acc[r][0] * a1v.x + acc[r][1] * a1v.y + acc[r][2] * a1v.z + acc[r][3] * a1v.w;
        float v2 = acc[r][0] * a2v.x + acc[r][1] * a2v.y + acc[r][2] * a2v.z + acc[r][3] * a2v.w;
#pragma unroll
        for (int off = 32; off; off >>= 1) {
            v1 += __shfl_xor(v1, off, 64);
            v2 += __shfl_xor(v2, off, 64);
        }
        if (lane == 0) {
            s1[row] = v1;
            s2[row] = v2;
        }
    }
}

// ---------------------------------------------------------------- KSORT2: 1 block x 1024 thr — hist+scan+scatter (NO rank)
__global__ __launch_bounds__(1024) void ksort2(
    const float* __restrict__ s2, int* __restrict__ perm,
    float* __restrict__ s2p, int* __restrict__ boff)
{
    __shared__ int A[NB];          // hist -> cursor
    __shared__ int temp[1024];
    const int t = threadIdx.x;

#pragma unroll
    for (int k = 0; k < NB / 1024; ++k) A[t + k * 1024] = 0;
    __syncthreads();

#pragma unroll
    for (int k = 0; k < NN / 1024; ++k)
        atomicAdd(&A[bucket_of(s2[t + k * 1024])], 1);
    __syncthreads();

    {   // exclusive scan of A in place (8 per thread + 1024-wide Hillis-Steele)
        const int base = t * 8;
        int loc[8];
        int s = 0;
#pragma unroll
        for (int k = 0; k < 8; ++k) { loc[k] = s; s += A[base + k]; }
        temp[t] = s;
        __syncthreads();
        for (int off = 1; off < 1024; off <<= 1) {
            const int v = (t >= off) ? temp[t - off] : 0;
            __syncthreads();
            temp[t] += v;
            __syncthreads();
        }
        const int excl = (t > 0) ? temp[t - 1] : 0;
#pragma unroll
        for (int k = 0; k < 8; ++k) {
            const int val = excl + loc[k];
            A[base + k] = val;       // cursor
            boff[base + k] = val;    // preserved bounds (global)
        }
        if (t == 0) boff[NB] = NN;
    }
    __syncthreads();

#pragma unroll
    for (int k = 0; k < NN / 1024; ++k) {            // scatter (bucket order)
        const int j = t + k * 1024;
        const float v = s2[j];
        const int p = atomicAdd(&A[bucket_of(v)], 1);
        perm[p] = j;
        s2p[p] = v;
    }
}

// ---------------------------------------------------------------- KD1: per-chunk totals, wave-per-chunk
__global__ __launch_bounds__(256) void kd1_tot(
    const float* __restrict__ h, const int* __restrict__ perm2,
    const float* __restrict__ s2p,
    float* __restrict__ TE, float* __restrict__ TF,
    float* __restrict__ sTE, float* __restrict__ sTF)
{
    const int w = threadIdx.x >> 6, lane = threadIdx.x & 63;
    const int c = blockIdx.x * 4 + w;
    const int p0 = c * POS;
    float vE[POS], vF[POS];
    int jj[POS];
#pragma unroll
    for (int k = 0; k < POS; ++k) {
        const float v = s2p[p0 + k];
        vE[k] = expf(v);
        vF[k] = expf(NEG_SLOPE * v);
        jj[k] = perm2[p0 + k];
    }
    float4 te = make_float4(0.f, 0.f, 0.f, 0.f);
    float4 tf = make_float4(0.f, 0.f, 0.f, 0.f);
#pragma unroll
    for (int k = 0; k < POS; ++k) {
        const float4 hv = *reinterpret_cast<const float4*>(&h[(size_t)jj[k] * DD + lane * 4]);
        te.x = fmaf(vE[k], hv.x, te.x); te.y = fmaf(vE[k], hv.y, te.y);
        te.z = fmaf(vE[k], hv.z, te.z); te.w = fmaf(vE[k], hv.w, te.w);
        tf.x = fmaf(vF[k], hv.x, tf.x); tf.y = fmaf(vF[k], hv.y, tf.y);
        tf.z = fmaf(vF[k], hv.z, tf.z); tf.w = fmaf(vF[k], hv.w, tf.w);
    }
    *reinterpret_cast<float4*>(&TE[(size_t)c * DD + lane * 4]) = te;
    *reinterpret_cast<float4*>(&TF[(size_t)c * DD + lane * 4]) = tf;
    if (lane == 0) {
        float se = 0.f, sf = 0.f;
#pragma unroll
        for (int k = 0; k < POS; ++k) { se += vE[k]; sf += vF[k]; }
        sTE[c] = se; sTF[c] = sf;
    }
}

// ---------------------------------------------------------------- 512-element exclusive scan, 256 threads
__device__ __forceinline__ void scan512_excl(float* lds, float* tmp, int t)
{
    const float a0 = lds[2 * t], a1 = lds[2 * t + 1];
    tmp[t] = a0 + a1;
    __syncthreads();
    for (int off = 1; off < 256; off <<= 1) {
        const float v = (t >= off) ? tmp[t - off] : 0.f;
        __syncthreads();
        tmp[t] += v;
        __syncthreads();
    }
    const float base = (t > 0) ? tmp[t - 1] : 0.f;
    lds[2 * t] = base;
    lds[2 * t + 1] = base + a0;
    __syncthreads();
}

// ---------------------------------------------------------------- KD2: chunk scans -> exclusive bases
// TE[c] := sum over chunks > c (suffix); TF[c] := sum over chunks < c (prefix).
__global__ __launch_bounds__(256) void kd2_scan(
    float* __restrict__ TE, float* __restrict__ TF,
    float* __restrict__ sTE, float* __restrict__ sTF)
{
    const int t = threadIdx.x;
    const int b = blockIdx.x;
    __shared__ float lds[CH];
    __shared__ float tmp[256];
    const int q0 = 2 * t, q1 = 2 * t + 1;

    if (b < 256) {
        const int d = b;
        lds[q0] = TE[(size_t)(511 - q0) * DD + d];
        lds[q1] = TE[(size_t)(511 - q1) * DD + d];
        __syncthreads();
        scan512_excl(lds, tmp, t);
        TE[(size_t)(511 - q0) * DD + d] = lds[q0];
        TE[(size_t)(511 - q1) * DD + d] = lds[q1];
        if (t == 0) TE[(size_t)CH * DD + d] = 0.f;
    } else if (b < 512) {
        const int d = b - 256;
        lds[q0] = TF[(size_t)q0 * DD + d];
        lds[q1] = TF[(size_t)q1 * DD + d];
        __syncthreads();
        scan512_excl(lds, tmp, t);
        TF[(size_t)q0 * DD + d] = lds[q0];
        TF[(size_t)q1 * DD + d] = lds[q1];
        if (t == 0) TF[(size_t)CH * DD + d] = tmp[255];
    } else {
        lds[q0] = sTE[511 - q0]; lds[q1] = sTE[511 - q1];
        __syncthreads();
        scan512_excl(lds, tmp, t);
        sTE[511 - q0] = lds[q0]; sTE[511 - q1] = lds[q1];
        if (t == 0) sTE[CH] = 0.f;
        __syncthreads();
        lds[q0] = sTF[q0]; lds[q1] = sTF[q1];
        __syncthreads();
        scan512_excl(lds, tmp, t);
        sTF[q0] = lds[q0]; sTF[q1] = lds[q1];
        if (t == 0) sTF[CH] = tmp[255];
    }
}

// ---------------------------------------------------------------- KE: output rows, wave-per-row
// Bt = bucket_of(tau) (O(1), no binary search). p0/p1 = boff[Bt]/boff[Bt+1].
// Enumerate full chunks ca..cb (ca=min(p0>>4,CH-1), cb=min(p1>>4,CH-1)),
// branching per element on s2 >= tau — exact for all elements in that range.
__global__ __launch_bounds__(256) void ke_out(
    const float* __restrict__ h, const float* __restrict__ s1,
    const float* __restrict__ s2p, const int* __restrict__ perm2,
    const int* __restrict__ boff,
    const float* __restrict__ TE, const float* __restrict__ TF,
    const float* __restrict__ sTE, const float* __restrict__ sTF,
    const float* __restrict__ ab, float* __restrict__ out)
{
    const int w = threadIdx.x >> 6, lane = threadIdx.x & 63;
    const int i = blockIdx.x * 4 + w;
    const float c = s1[i] + ab[0];
    const float tau = -c;
    const float A = expf(c);
    const float Alo = expf(NEG_SLOPE * c);

    const int Bt = bucket_of(tau);
    const int p0 = boff[Bt], p1 = boff[Bt + 1];
    const int ca = min(p0 >> 4, CH - 1);
    const int cb = min(p1 >> 4, CH - 1);

    float4 numE = *reinterpret_cast<const float4*>(&TE[(size_t)cb * DD + lane * 4]);
    float4 numF = *reinterpret_cast<const float4*>(&TF[(size_t)ca * DD + lane * 4]);
    float denE = sTE[cb];
    float denF = sTF[ca];

    const int pEnd = (cb + 1) * POS;
    for (int p = ca * POS; p < pEnd; ++p) {
        const float v = s2p[p];
        const int j = perm2[p];
        const float4 hv = *reinterpret_cast<const float4*>(&h[(size_t)j * DD + lane * 4]);
        if (v >= tau) {
            const float e = expf(v);
            numE.x = fmaf(e, hv.x, numE.x); numE.y = fmaf(e, hv.y, numE.y);
            numE.z = fmaf(e, hv.z, numE.z); numE.w = fmaf(e, hv.w, numE.w);
            denE += e;
        } else {
            const float f = expf(NEG_SLOPE * v);
            numF.x = fmaf(f, hv.x, numF.x); numF.y = fmaf(f, hv.y, numF.y);
            numF.z = fmaf(f, hv.z, numF.z); numF.w = fmaf(f, hv.w, numF.w);
            denF += f;
        }
    }

    const float inv = 1.f / fmaf(A, denE, Alo * denF);
    float4 o;
    o.x = fmaf(A, numE.x, Alo * numF.x) * inv;
    o.y = fmaf(A, numE.y, Alo * numF.y) * inv;
    o.z = fmaf(A, numE.z, Alo * numF.z) * inv;
    o.w = fmaf(A, numE.w, Alo * numF.w) * inv;
    *reinterpret_cast<float4*>(&out[(size_t)i * DD + lane * 4]) = o;
}

// ----------------------------------------------------------------
extern "C" void kernel_launch(void* const* d_in, const int* in_sizes, int n_in,
                              void* d_out, int out_size, void* d_ws, size_t ws_size,
                              hipStream_t stream)
{
    const float* x   = (const float*)d_in[0];
    const float* W   = (const float*)d_in[1];
    const float* bfc = (const float*)d_in[2];
    const float* a1  = (const float*)d_in[3];
    const float* a2  = (const float*)d_in[4];
    const float* ab  = (const float*)d_in[5];
    float* out = (float*)d_out;

    float* h    = (float*)d_ws;                    // [N][D]
    float* TE   = h + (size_t)NN * DD;             // [CH+1][D]
    float* TF   = TE + (size_t)(CH + 1) * DD;      // [CH+1][D]
    float* s1   = TF + (size_t)(CH + 1) * DD;      // [N]
    float* s2   = s1 + NN;                         // [N]
    float* s2p  = s2 + NN;                         // [N] bucket-ordered values
    float* sTE  = s2p + NN;                        // [CH+1]
    float* sTF  = sTE + (CH + 1);                  // [CH+1]
    int* perm   = (int*)(sTF + (CH + 1));          // [N]
    int* boff   = perm + NN;                       // [NB+1]

    ka_gemm <<<NN / 16, 256, 0, stream>>>(x, W, bfc, a1, a2, h, s1, s2);
    ksort2  <<<1, 1024, 0, stream>>>(s2, perm, s2p, boff);
    kd1_tot <<<CH / 4, 256, 0, stream>>>(h, perm, s2p, TE, TF, sTE, sTF);
    kd2_scan<<<513, 256, 0, stream>>>(TE, TF, sTE, sTF);
    ke_out  <<<NN / 4, 256, 0, stream>>>(h, s1, s2p, perm, boff, TE, TF, sTE, sTF, ab, out);
}